// Round 3
// baseline (134.391 us; speedup 1.0000x reference)
//
#include <hip/hip_runtime.h>

// Problem constants (from setup_inputs): B=16, NEG=128, S=128, D=512, N_PRED=12
#define DIM 512
#define M_ROWS 2048      // B*S
#define BM 64
#define BN 64
#define BK 16

// ---------------- Kernel 1: c_proj = c @ W[k]^T + b[k] ----------------
// M=2048, N=512, K=512. A[m,k]=c, B[o,k]=W[k_sel][o][k] (both row-contig in k).
// Software-pipelined: next K-tile's global loads issue before the FMA burst.
__global__ __launch_bounds__(256) void cproj_kernel(
    const float* __restrict__ c, const float* __restrict__ W,
    const float* __restrict__ bias, const int* __restrict__ kptr,
    float* __restrict__ cp) {
    const int ksel = kptr[0];
    const float* __restrict__ Wk = W + (size_t)ksel * DIM * DIM;
    const float* __restrict__ bk = bias + (size_t)ksel * DIM;

    __shared__ float As[BK][BM];
    __shared__ float Bs[BK][BN];

    const int bm = blockIdx.x % (M_ROWS / BM);   // 0..31
    const int bn = blockIdx.x / (M_ROWS / BM);   // 0..7
    const int t  = threadIdx.x;

    // staging: 64 rows x 16 k each tile; 256 threads load float4 each
    const int lrow = t >> 2;          // 0..63
    const int lk4  = (t & 3) * 4;     // 0,4,8,12
    // compute mapping: 16x16 threads, each 4x4 outputs
    const int tm = (t & 15) * 4;
    const int tn = (t >> 4) * 4;

    float acc[4][4] = {};

    const float* Arow = c  + (size_t)(bm * BM + lrow) * DIM + lk4;
    const float* Brow = Wk + (size_t)(bn * BN + lrow) * DIM + lk4;

    // prologue load (k0 = 0)
    float4 a4 = *(const float4*)Arow;
    float4 b4 = *(const float4*)Brow;

    for (int k0 = 0; k0 < DIM; k0 += BK) {
        __syncthreads();   // previous iteration's LDS reads complete
        As[lk4 + 0][lrow] = a4.x; As[lk4 + 1][lrow] = a4.y;
        As[lk4 + 2][lrow] = a4.z; As[lk4 + 3][lrow] = a4.w;
        Bs[lk4 + 0][lrow] = b4.x; Bs[lk4 + 1][lrow] = b4.y;
        Bs[lk4 + 2][lrow] = b4.z; Bs[lk4 + 3][lrow] = b4.w;
        __syncthreads();
        // prefetch next tile while this tile computes (latency hidden)
        if (k0 + BK < DIM) {
            a4 = *(const float4*)(Arow + k0 + BK);
            b4 = *(const float4*)(Brow + k0 + BK);
        }
#pragma unroll
        for (int kk = 0; kk < BK; ++kk) {
            const float4 av = *(const float4*)&As[kk][tm];
            const float4 bv = *(const float4*)&Bs[kk][tn];
            const float a[4] = {av.x, av.y, av.z, av.w};
            const float b[4] = {bv.x, bv.y, bv.z, bv.w};
#pragma unroll
            for (int i = 0; i < 4; ++i)
#pragma unroll
                for (int j = 0; j < 4; ++j)
                    acc[i][j] = fmaf(a[i], b[j], acc[i][j]);
        }
    }

    const float4 bb = *(const float4*)(bk + bn * BN + tn);
    const float badd[4] = {bb.x, bb.y, bb.z, bb.w};
#pragma unroll
    for (int i = 0; i < 4; ++i) {
        float4 r;
        r.x = acc[i][0] + badd[0];
        r.y = acc[i][1] + badd[1];
        r.z = acc[i][2] + badd[2];
        r.w = acc[i][3] + badd[3];
        *(float4*)(cp + (size_t)(bm * BM + tm + i) * DIM + bn * BN + tn) = r;
    }
}

// ---------------- Kernel 2: out[b,n,s] = (1/512) * dot(cp[b,s,:], z[b,n,s,:]) ----
// One block per (b,s) row: cp row lives in registers (8 floats/lane), loaded ONCE.
// 4 waves each stream 32 negatives; z reads fully coalesced (2 KB/wave/n);
// 1-deep software prefetch hides HBM latency under the reduce.
#define N_STRIDE ((size_t)4 * 128 * 512)   // 4 negatives ahead in z
__global__ __launch_bounds__(256) void dot_kernel(
    const float* __restrict__ z, const float* __restrict__ cp,
    float* __restrict__ out) {
    const int bs   = blockIdx.x;             // b*128 + s (0..2047)
    const int wave = threadIdx.x >> 6;       // 0..3
    const int lane = threadIdx.x & 63;
    const int b = bs >> 7;
    const int s = bs & 127;

    // cp row -> registers (all 4 waves broadcast-read the same 2 KB via L1)
    const float* cpr = cp + (size_t)bs * DIM + lane * 8;
    const float4 c0 = *(const float4*)cpr;
    const float4 c1 = *(const float4*)(cpr + 4);

    // wave handles n = wave, wave+4, ..., wave+124
    const float* zp = z + (((size_t)(b * 128 + wave)) * 128 + s) * DIM + lane * 8;
    float4 z0 = *(const float4*)zp;
    float4 z1 = *(const float4*)(zp + 4);

    float* outp = out + ((size_t)b * 128 + wave) * 128 + s;

#pragma unroll 4
    for (int i = 0; i < 32; ++i) {
        const float4 y0 = z0, y1 = z1;
        if (i < 31) {   // prefetch next n while reducing current
            zp += N_STRIDE;
            z0 = *(const float4*)zp;
            z1 = *(const float4*)(zp + 4);
        }
        float acc = y0.x * c0.x;
        acc = fmaf(y0.y, c0.y, acc);
        acc = fmaf(y0.z, c0.z, acc);
        acc = fmaf(y0.w, c0.w, acc);
        acc = fmaf(y1.x, c1.x, acc);
        acc = fmaf(y1.y, c1.y, acc);
        acc = fmaf(y1.z, c1.z, acc);
        acc = fmaf(y1.w, c1.w, acc);
#pragma unroll
        for (int off = 32; off; off >>= 1) acc += __shfl_xor(acc, off);
        if (lane == 0) outp[(size_t)i * 4 * 128] = acc * (1.0f / 512.0f);
    }
}

extern "C" void kernel_launch(void* const* d_in, const int* in_sizes, int n_in,
                              void* d_out, int out_size, void* d_ws, size_t ws_size,
                              hipStream_t stream) {
    const float* c    = (const float*)d_in[0];
    const float* z    = (const float*)d_in[1];
    const float* W    = (const float*)d_in[2];
    const float* bias = (const float*)d_in[3];
    const int*   kptr = (const int*)d_in[4];
    float* out = (float*)d_out;
    float* cp  = (float*)d_ws;   // 2048*512*4 = 4 MB scratch for c_proj

    // Kernel 1: 32 M-tiles x 8 N-tiles = 256 blocks
    cproj_kernel<<<dim3(256), dim3(256), 0, stream>>>(c, W, bias, kptr, cp);
    // Kernel 2: one block per (b,s) row = 2048 blocks, 4 waves each
    dot_kernel<<<dim3(2048), dim3(256), 0, stream>>>(z, cp, out);
}

// Round 4
// 123.493 us; speedup vs baseline: 1.0882x; 1.0882x over previous
//
#include <hip/hip_runtime.h>

// Problem constants: B=16, NEG=128, S=128, D=512, N_PRED=12
#define DIM 512
#define M_ROWS 2048      // B*S

typedef __attribute__((ext_vector_type(8))) short short8;   // 8 bf16 (4 VGPRs)
typedef __attribute__((ext_vector_type(4))) float f32x4;

// f32 -> bf16 round-to-nearest-even (inputs are well-scaled, no NaN expected)
static __device__ __forceinline__ short f2bf(float x) {
    unsigned int u = __builtin_bit_cast(unsigned int, x);
    u += 0x7fffu + ((u >> 16) & 1u);
    return (short)(u >> 16);
}

// ---------------- Kernel 1: c_proj = c @ W[k]^T + b[k], bf16 MFMA ----------------
// M=2048, N=512, K=512. A[m,k]=c, B[o,k]=W[ksel][o][k] (both row-contig in k).
// 32 m-tiles x 8 n-tiles = 256 blocks; 4 waves/block, wave w owns output cols w*16..+15.
// LDS rows padded to 40 shorts (80 B): fragment ds_read_b128 lands 2-way on banks (free).
#define K1_PAD 40
__global__ __launch_bounds__(256) void cproj_mfma(
    const float* __restrict__ c, const float* __restrict__ W,
    const float* __restrict__ bias, const int* __restrict__ kptr,
    float* __restrict__ cp) {
    const int ksel = kptr[0];
    const float* __restrict__ Wk = W + (size_t)ksel * DIM * DIM;
    const float* __restrict__ bk = bias + (size_t)ksel * DIM;

    __shared__ short Alds[64][K1_PAD];
    __shared__ short Blds[64][K1_PAD];

    const int bm = blockIdx.x & 31;     // m-tile (64 rows)
    const int bn = blockIdx.x >> 5;     // n-tile (64 cols)
    const int t  = threadIdx.x;
    const int lane = t & 63;
    const int wv   = t >> 6;            // wave 0..3

    // staging: each thread loads 8 f32 of A and 8 of B per K-step
    const int srow = t >> 2;            // 0..63
    const int sk   = (t & 3) * 8;       // 0,8,16,24

    const float* Ap = c  + (size_t)(bm * 64 + srow) * DIM + sk;
    const float* Bp = Wk + (size_t)(bn * 64 + srow) * DIM + sk;

    // prologue load (k-step 0)
    float4 a0 = *(const float4*)Ap,       a1 = *(const float4*)(Ap + 4);
    float4 b0 = *(const float4*)Bp,       b1 = *(const float4*)(Bp + 4);

    f32x4 acc[4] = {};                  // 4 m-subtiles of 16x16

    // fragment addressing: non-K index = lane&15, K-offset = (lane>>4)*8
    const int frow = lane & 15;
    const int fk   = (lane >> 4) * 8;

    for (int step = 0; step < 16; ++step) {
        __syncthreads();                // previous step's frag reads complete
        short8 av, bv;
        av[0] = f2bf(a0.x); av[1] = f2bf(a0.y); av[2] = f2bf(a0.z); av[3] = f2bf(a0.w);
        av[4] = f2bf(a1.x); av[5] = f2bf(a1.y); av[6] = f2bf(a1.z); av[7] = f2bf(a1.w);
        bv[0] = f2bf(b0.x); bv[1] = f2bf(b0.y); bv[2] = f2bf(b0.z); bv[3] = f2bf(b0.w);
        bv[4] = f2bf(b1.x); bv[5] = f2bf(b1.y); bv[6] = f2bf(b1.z); bv[7] = f2bf(b1.w);
        *(short8*)&Alds[srow][sk] = av;
        *(short8*)&Blds[srow][sk] = bv;
        __syncthreads();
        // prefetch next K-step's f32 while MFMAs run
        if (step < 15) {
            const int off = (step + 1) * 32;
            a0 = *(const float4*)(Ap + off); a1 = *(const float4*)(Ap + off + 4);
            b0 = *(const float4*)(Bp + off); b1 = *(const float4*)(Bp + off + 4);
        }
        const short8 bfrag = *(const short8*)&Blds[wv * 16 + frow][fk];
#pragma unroll
        for (int f = 0; f < 4; ++f) {
            const short8 afrag = *(const short8*)&Alds[f * 16 + frow][fk];
            acc[f] = __builtin_amdgcn_mfma_f32_16x16x32_bf16(afrag, bfrag, acc[f], 0, 0, 0);
        }
    }

    // epilogue: C/D layout col=lane&15, row=(lane>>4)*4+reg  [m89-verified]
    const int col = bn * 64 + wv * 16 + frow;
    const float bias_v = bk[col];
    const int r0 = (lane >> 4) * 4;
#pragma unroll
    for (int f = 0; f < 4; ++f)
#pragma unroll
        for (int r = 0; r < 4; ++r)
            cp[(size_t)(bm * 64 + f * 16 + r0 + r) * DIM + col] = acc[f][r] + bias_v;
}

// ---------------- Kernel 2: out[b,n,s] = (1/512) * dot(cp[b,s,:], z[b,n,s,:]) ----
// One block per (b,s) row: cp row lives in registers (8 floats/lane), loaded ONCE.
// 4 waves each stream 32 negatives; z reads fully coalesced (2 KB/wave/n);
// 1-deep software prefetch hides HBM latency under the reduce.
#define N_STRIDE ((size_t)4 * 128 * 512)   // 4 negatives ahead in z
__global__ __launch_bounds__(256) void dot_kernel(
    const float* __restrict__ z, const float* __restrict__ cp,
    float* __restrict__ out) {
    const int bs   = blockIdx.x;             // b*128 + s (0..2047)
    const int wave = threadIdx.x >> 6;       // 0..3
    const int lane = threadIdx.x & 63;
    const int b = bs >> 7;
    const int s = bs & 127;

    // cp row -> registers (all 4 waves broadcast-read the same 2 KB via L1)
    const float* cpr = cp + (size_t)bs * DIM + lane * 8;
    const float4 c0 = *(const float4*)cpr;
    const float4 c1 = *(const float4*)(cpr + 4);

    // wave handles n = wave, wave+4, ..., wave+124
    const float* zp = z + (((size_t)(b * 128 + wave)) * 128 + s) * DIM + lane * 8;
    float4 z0 = *(const float4*)zp;
    float4 z1 = *(const float4*)(zp + 4);

    float* outp = out + ((size_t)b * 128 + wave) * 128 + s;

#pragma unroll 4
    for (int i = 0; i < 32; ++i) {
        const float4 y0 = z0, y1 = z1;
        if (i < 31) {   // prefetch next n while reducing current
            zp += N_STRIDE;
            z0 = *(const float4*)zp;
            z1 = *(const float4*)(zp + 4);
        }
        float acc = y0.x * c0.x;
        acc = fmaf(y0.y, c0.y, acc);
        acc = fmaf(y0.z, c0.z, acc);
        acc = fmaf(y0.w, c0.w, acc);
        acc = fmaf(y1.x, c1.x, acc);
        acc = fmaf(y1.y, c1.y, acc);
        acc = fmaf(y1.z, c1.z, acc);
        acc = fmaf(y1.w, c1.w, acc);
#pragma unroll
        for (int off = 32; off; off >>= 1) acc += __shfl_xor(acc, off);
        if (lane == 0) outp[(size_t)i * 4 * 128] = acc * (1.0f / 512.0f);
    }
}

extern "C" void kernel_launch(void* const* d_in, const int* in_sizes, int n_in,
                              void* d_out, int out_size, void* d_ws, size_t ws_size,
                              hipStream_t stream) {
    const float* c    = (const float*)d_in[0];
    const float* z    = (const float*)d_in[1];
    const float* W    = (const float*)d_in[2];
    const float* bias = (const float*)d_in[3];
    const int*   kptr = (const int*)d_in[4];
    float* out = (float*)d_out;
    float* cp  = (float*)d_ws;   // 2048*512*4 = 4 MB scratch for c_proj

    // Kernel 1: 32 M-tiles x 8 N-tiles = 256 blocks, bf16 MFMA
    cproj_mfma<<<dim3(256), dim3(256), 0, stream>>>(c, W, bias, kptr, cp);
    // Kernel 2: one block per (b,s) row = 2048 blocks, 4 waves each
    dot_kernel<<<dim3(2048), dim3(256), 0, stream>>>(z, cp, out);
}